// Round 13
// baseline (284.504 us; speedup 1.0000x reference)
//
#include <hip/hip_runtime.h>

#define GRID_D 64
#define NN (GRID_D * GRID_D)   // 4096 nodes per image
#define H 64
#define C_IN 12
#define B_SZ 128
#define LN_EPS 1e-5f

typedef _Float16 f16x8 __attribute__((ext_vector_type(8)));
typedef _Float16 f16x4 __attribute__((ext_vector_type(4)));
typedef float    f32x4 __attribute__((ext_vector_type(4)));

#define AS1 __attribute__((address_space(1)))
#define AS3 __attribute__((address_space(3)))

// ---------------------------------------------------------------------------
// Kernel 0: weight prep — plain-transposed f16 copies of Ws/Wn.
// wt[l][g][j][k] = W[l,g][k][j]
// ---------------------------------------------------------------------------
__global__ __launch_bounds__(256) void k_prep(
    const float* __restrict__ ws_, const float* __restrict__ wn_,
    _Float16* __restrict__ wt)
{
    int i = blockIdx.x * 256 + threadIdx.x;      // 0..24575
    if (i < 3 * 2 * 4096) {
        int l = i >> 13, g = (i >> 12) & 1, j = (i >> 6) & 63, k = i & 63;
        const float* W = (g ? wn_ : ws_) + l * 4096;
        wt[i] = (_Float16)W[k * 64 + j];
    }
}

// ---------------------------------------------------------------------------
// Kernel 1: FUSED input projection + layer 1.
// Block = 256 thr (4 waves) owns one grid row r of one image. Computes h0
// rows r-1,r,r+1 in-register from x (C=12 projection, cheap 3x redundancy),
// stores swizzled f16 in LDS, then layer-1 MFMA (operand-swapped, weights in
// VGPRs) + LN + residual ReLU -> h1 global (plain layout). h0 never hits HBM.
// ---------------------------------------------------------------------------
__global__ __launch_bounds__(256, 2) void k_inl1(
    const float* __restrict__ x, const float* __restrict__ w_in,
    const float* __restrict__ b_in,
    const _Float16* __restrict__ wtb,      // layer0 [2][64 j][64 k] transposed
    const float* __restrict__ cb, const float* __restrict__ lg,
    const float* __restrict__ lb,
    _Float16* __restrict__ h1)
{
    __shared__ _Float16 st[3][4096];       // h0 rows r-1,r,r+1 swizzled (24KB)
    __shared__ float xs[C_IN][192];        // x rows r-1,r,r+1 (9KB)
    __shared__ float ws[C_IN][64];
    __shared__ float bs[64];
    __shared__ float pr[192];              // cb|lg|lb layer 0

    int bid = blockIdx.x, b = bid >> 6, r = bid & 63;
    int tid = threadIdx.x;
    const float* xb = x + (size_t)b * C_IN * NN;

    for (int idx = tid; idx < C_IN * 192; idx += 256) {
        int c = idx / 192, q = idx - c * 192;
        int rr = q >> 6, cc = q & 63;
        int grow = r - 1 + rr;
        xs[c][q] = ((unsigned)grow < 64u) ? xb[(size_t)c * NN + grow * 64 + cc] : 0.f;
    }
    for (int idx = tid; idx < C_IN * 64; idx += 256) ws[idx >> 6][idx & 63] = w_in[idx];
    if (tid < 64) bs[tid] = b_in[tid];
    else if (tid < 256) {
        int t2 = tid - 64;   // 0..191
        pr[t2] = (t2 < 64) ? cb[t2] : (t2 < 128) ? lg[t2 - 64] : lb[t2 - 128];
    }

    int ln = tid & 63, wv = tid >> 6;
    int lrow = ln & 15, kgrp = ln >> 4, kq = kgrp * 4;

    // layer-0 weight frags -> VGPRs (64), pinned
    f16x8 wsf[2][4], wnf[2][4];
    #pragma unroll
    for (int ks = 0; ks < 2; ++ks) {
        int k0 = ks * 32 + kq * 2;
        #pragma unroll
        for (int ft = 0; ft < 4; ++ft) {
            int j = ft * 16 + lrow;
            wsf[ks][ft] = *(const f16x8*)(wtb + (j << 6) + k0);
            wnf[ks][ft] = *(const f16x8*)(wtb + ((64 + j) << 6) + k0);
        }
    }
    #pragma unroll
    for (int ks = 0; ks < 2; ++ks)
        #pragma unroll
        for (int ft = 0; ft < 4; ++ft)
            asm volatile("" : "+v"(wsf[ks][ft]), "+v"(wnf[ks][ft]));
    __syncthreads();

    // ---- compute h0 rows r-1,r,r+1 into swizzled LDS ----
    {
        int n = tid >> 2, j0 = (tid & 3) * 16;
        int sl0 = (((j0 >> 3) ^ (n & 7)) << 3);
        int sl1 = ((((j0 >> 3) + 1) ^ (n & 7)) << 3);
        #pragma unroll
        for (int rr = 0; rr < 3; ++rr) {
            int grow = r - 1 + rr;
            float acc[16];
            #pragma unroll
            for (int t = 0; t < 16; ++t) acc[t] = bs[j0 + t];
            #pragma unroll
            for (int c = 0; c < C_IN; ++c) {
                float xv = xs[c][rr * 64 + n];
                #pragma unroll
                for (int t = 0; t < 16; ++t) acc[t] += xv * ws[c][j0 + t];
            }
            bool ok = ((unsigned)grow < 64u);    // OOB rows must be ZERO
            f16x8 lo, hi;
            #pragma unroll
            for (int t = 0; t < 8; ++t) {
                lo[t] = ok ? (_Float16)acc[t]     : (_Float16)0.f;
                hi[t] = ok ? (_Float16)acc[8 + t] : (_Float16)0.f;
            }
            _Float16* dst = &st[rr][n << 6];
            *(f16x8*)(dst + sl0) = lo;
            *(f16x8*)(dst + sl1) = hi;
        }
    }
    __syncthreads();

    // ---- layer 1: 4 waves, wave = 16-col tile ----
    int col = wv * 16 + lrow;
    int cs = lrow & 7;
    bool cl = (col > 0), cr = (col < 63);
    _Float16 hinv = (_Float16)(1.0f / (float)((r > 0) + (r < 63) + cl + cr));
    const _Float16* rc = &st[1][0];
    const _Float16* ru = &st[0][0];    // zeroed if r==0
    const _Float16* rd = &st[2][0];    // zeroed if r==63

    f32x4 acc[4];
    #pragma unroll
    for (int ft = 0; ft < 4; ++ft) acc[ft] = (f32x4){0.f, 0.f, 0.f, 0.f};

    #pragma unroll
    for (int ks = 0; ks < 2; ++ks) {
        int sl = ((ks * 4 + kgrp) ^ cs) << 3;
        f16x8 a = *(const f16x8*)(rc + (col << 6) + sl);
        #pragma unroll
        for (int ft = 0; ft < 4; ++ft)
            acc[ft] = __builtin_amdgcn_mfma_f32_16x16x32_f16(wsf[ks][ft], a, acc[ft], 0, 0, 0);
    }
    #pragma unroll
    for (int ks = 0; ks < 2; ++ks) {
        int c8 = ks * 4 + kgrp;
        int sl = (c8 ^ cs) << 3;
        f16x8 z = {};
        f16x8 u = *(const f16x8*)(ru + (col << 6) + sl);
        f16x8 d = *(const f16x8*)(rd + (col << 6) + sl);
        int cm = col - cl;
        f16x8 lv = *(const f16x8*)(rc + (cm << 6) + ((c8 ^ (cm & 7)) << 3));
        if (!cl) lv = z;
        int cp = col + cr;
        f16x8 rv = *(const f16x8*)(rc + (cp << 6) + ((c8 ^ (cp & 7)) << 3));
        if (!cr) rv = z;
        f16x8 sm = (lv + rv) + (u + d);
        f16x8 g;
        #pragma unroll
        for (int e = 0; e < 8; ++e) g[e] = sm[e] * hinv;
        #pragma unroll
        for (int ft = 0; ft < 4; ++ft)
            acc[ft] = __builtin_amdgcn_mfma_f32_16x16x32_f16(wnf[ks][ft], g, acc[ft], 0, 0, 0);
    }

    // epilogue: +bias, LN, residual(h0 self) + ReLU, store h1 (plain layout)
    float s1 = 0.f, s2 = 0.f;
    #pragma unroll
    for (int ft = 0; ft < 4; ++ft) {
        f32x4 qv = *(const f32x4*)&pr[ft * 16 + kq];
        acc[ft] += qv;
        #pragma unroll
        for (int t = 0; t < 4; ++t) { float xv = acc[ft][t]; s1 += xv; s2 += xv * xv; }
    }
    s1 += __shfl_xor(s1, 16); s1 += __shfl_xor(s1, 32);
    s2 += __shfl_xor(s2, 16); s2 += __shfl_xor(s2, 32);
    float mu   = s1 * (1.0f / H);
    float var  = s2 * (1.0f / H) - mu * mu;
    float rstd = rsqrtf(var + LN_EPS);

    _Float16* hp = h1 + (((size_t)(b * NN + r * GRID_D + col)) << 6);
    #pragma unroll
    for (int ft = 0; ft < 4; ++ft) {
        f32x4 lgq = *(const f32x4*)&pr[64 + ft * 16 + kq];
        f32x4 lbq = *(const f32x4*)&pr[128 + ft * 16 + kq];
        int slot = (ft * 2 + (kgrp >> 1)) ^ cs;
        f16x4 rq = *(const f16x4*)(rc + (col << 6) + (slot << 3) + (kgrp & 1) * 4);
        f16x4 oq;
        #pragma unroll
        for (int t = 0; t < 4; ++t) {
            float o = (float)rq[t]
                    + fmaxf((acc[ft][t] - mu) * rstd * lgq[t] + lbq[t], 0.f);
            oq[t] = (_Float16)o;
        }
        *(f16x4*)(hp + ft * 16 + kq) = oq;
    }
}

// stage one h1 row (64 nodes x 64 f16 = 8KB) into a ring slot; linear dest,
// pre-swizzled per-lane global source (rule 21). 8 waves cover the row.
__device__ __forceinline__ void stage_row(
    const _Float16* hb, int grow, _Float16* slot, int wv, int ln)
{
    const _Float16* src = hb
        + (((size_t)(grow * GRID_D + wv * 8 + (ln >> 3))) << 6)
        + (((ln & 7) ^ (ln >> 3)) << 3);
    _Float16* dst = slot + wv * 512;
    __builtin_amdgcn_global_load_lds((const AS1 void*)src, (AS3 void*)dst, 16, 0, 0);
}

// ---------------------------------------------------------------------------
// Kernel 2: FUSED layers 2+3+head. Block = 512 thr (8 waves) owns 16 output
// rows of one image; grid 512 = 2 blocks/CU (16 waves, needs only VGPR<=128).
// Pipeline: step s stages h1 row p=r0-2+s (async, all 8 waves); grpA (waves
// 0-3, layer 2) computes row p-2 ring1->ring2; grpB (waves 4-7, layer3+head)
// computes row p-4 ring2->logits. 4-slot rings, one barrier/step, 22 steps.
// h2 never leaves LDS. Weights: 16 f16x8/lane in VGPRs, pinned.
// ---------------------------------------------------------------------------
__global__ __launch_bounds__(512, 2) void k_fused2(
    const _Float16* __restrict__ h1, float* __restrict__ logits,
    const _Float16* __restrict__ wtb,      // [3][2][64][64]; layers 1,2 used
    const float* __restrict__ cb, const float* __restrict__ lg,
    const float* __restrict__ lb,
    const float* __restrict__ w_head, const float* __restrict__ b_head)
{
    __shared__ _Float16 ring1[4 * 4096];   // 32 KB (h1, staged)
    __shared__ _Float16 ring2[4 * 4096];   // 32 KB (h2)
    __shared__ float    pl[448];           // L1 params | L2 params | w_head

    int tid = threadIdx.x, ln = tid & 63, wv = tid >> 6;
    int bid = blockIdx.x;
    int img = bid >> 2, chunk = bid & 3;
    int r0 = chunk << 4;                   // 16 owned output rows
    const _Float16* hg = h1 + ((size_t)img << 18);

    int grp = wv >> 2;                     // 0 = layer2, 1 = layer3+head
    int ct  = wv & 3;
    int lrow = ln & 15, kgrp = ln >> 4, kq = kgrp * 4;
    int col = ct * 16 + lrow;
    int cs = lrow & 7;
    bool cl = (col > 0), cr = (col < 63);

    // ---- weights (layer grp+1): 16 frags = 64 VGPR, pinned ----
    const _Float16* wg = wtb + (grp + 1) * 8192;
    f16x8 wsf[2][4], wnf[2][4];
    #pragma unroll
    for (int ks = 0; ks < 2; ++ks) {
        int k0 = ks * 32 + kq * 2;
        #pragma unroll
        for (int ft = 0; ft < 4; ++ft) {
            int j = ft * 16 + lrow;
            wsf[ks][ft] = *(const f16x8*)(wg + (j << 6) + k0);
            wnf[ks][ft] = *(const f16x8*)(wg + ((64 + j) << 6) + k0);
        }
    }
    #pragma unroll
    for (int ks = 0; ks < 2; ++ks)
        #pragma unroll
        for (int ft = 0; ft < 4; ++ft)
            asm volatile("" : "+v"(wsf[ks][ft]), "+v"(wnf[ks][ft]));

    // ---- params ----
    if (tid < 384) {
        int l = tid / 192 + 1, rr = tid % 192;
        pl[tid] = (rr < 64) ? cb[l * 64 + rr]
                : (rr < 128) ? lg[l * 64 + rr - 64] : lb[l * 64 + rr - 128];
    } else if (tid < 448) {
        pl[tid] = w_head[tid - 384];
    }
    __syncthreads();

    const float* myp = pl + grp * 192;
    float bh = b_head[0];

    int lo0 = (r0 - 2 < 0) ? 0 : r0 - 2;
    int hi0 = (r0 + 17 > 63) ? 63 : r0 + 17;
    int loC = grp ? r0 : ((r0 - 1 < 0) ? 0 : r0 - 1);
    int hiC = grp ? (r0 + 15) : ((r0 + 16 > 63) ? 63 : r0 + 16);
    const _Float16* rin = grp ? ring2 : ring1;

    #pragma unroll 1
    for (int s = 0; s <= 21; ++s) {
        int p = r0 - 2 + s;
        if (p >= lo0 && p <= hi0)
            stage_row(hg, p, ring1 + ((p & 3) << 12), wv, ln);

        int q = p - 2 - 2 * grp;               // my row this step
        if (q >= loC && q <= hiC) {
            _Float16 hinv = (_Float16)(1.0f / (float)((q > 0) + (q < 63) + cl + cr));
            f16x8 z = {};
            const _Float16* rc = rin + ((q & 3) << 12);
            const _Float16* ru = rin + (((q - 1) & 3) << 12);
            const _Float16* rd = rin + (((q + 1) & 3) << 12);

            f32x4 acc[4];
            #pragma unroll
            for (int ft = 0; ft < 4; ++ft) acc[ft] = (f32x4){0.f, 0.f, 0.f, 0.f};

            #pragma unroll
            for (int ks = 0; ks < 2; ++ks) {
                int sl = ((ks * 4 + kgrp) ^ cs) << 3;
                f16x8 a = *(const f16x8*)(rc + (col << 6) + sl);
                #pragma unroll
                for (int ft = 0; ft < 4; ++ft)
                    acc[ft] = __builtin_amdgcn_mfma_f32_16x16x32_f16(wsf[ks][ft], a, acc[ft], 0, 0, 0);
            }
            #pragma unroll
            for (int ks = 0; ks < 2; ++ks) {
                int c8 = ks * 4 + kgrp;
                int sl = (c8 ^ cs) << 3;
                f16x8 u = (q > 0)  ? *(const f16x8*)(ru + (col << 6) + sl) : z;
                f16x8 d = (q < 63) ? *(const f16x8*)(rd + (col << 6) + sl) : z;
                int cm = col - cl;
                f16x8 lv = *(const f16x8*)(rc + (cm << 6) + ((c8 ^ (cm & 7)) << 3));
                if (!cl) lv = z;
                int cp = col + cr;
                f16x8 rv = *(const f16x8*)(rc + (cp << 6) + ((c8 ^ (cp & 7)) << 3));
                if (!cr) rv = z;
                f16x8 sm = (lv + rv) + (u + d);
                f16x8 g;
                #pragma unroll
                for (int e = 0; e < 8; ++e) g[e] = sm[e] * hinv;
                #pragma unroll
                for (int ft = 0; ft < 4; ++ft)
                    acc[ft] = __builtin_amdgcn_mfma_f32_16x16x32_f16(wnf[ks][ft], g, acc[ft], 0, 0, 0);
            }

            // epilogue
            float s1 = 0.f, s2 = 0.f;
            #pragma unroll
            for (int ft = 0; ft < 4; ++ft) {
                f32x4 qv = *(const f32x4*)&myp[ft * 16 + kq];
                acc[ft] += qv;
                #pragma unroll
                for (int t = 0; t < 4; ++t) { float xv = acc[ft][t]; s1 += xv; s2 += xv * xv; }
            }
            s1 += __shfl_xor(s1, 16); s1 += __shfl_xor(s1, 32);
            s2 += __shfl_xor(s2, 16); s2 += __shfl_xor(s2, 32);
            float mu   = s1 * (1.0f / H);
            float var  = s2 * (1.0f / H) - mu * mu;
            float rstd = rsqrtf(var + LN_EPS);

            if (grp == 0) {
                _Float16* outp = ring2 + ((q & 3) << 12) + (col << 6);
                #pragma unroll
                for (int ft = 0; ft < 4; ++ft) {
                    f32x4 lgq = *(const f32x4*)&myp[64 + ft * 16 + kq];
                    f32x4 lbq = *(const f32x4*)&myp[128 + ft * 16 + kq];
                    int slot = (ft * 2 + (kgrp >> 1)) ^ cs;
                    f16x4 rq = *(const f16x4*)(rc + (col << 6) + (slot << 3) + (kgrp & 1) * 4);
                    f16x4 oq;
                    #pragma unroll
                    for (int t = 0; t < 4; ++t) {
                        float o = (float)rq[t]
                                + fmaxf((acc[ft][t] - mu) * rstd * lgq[t] + lbq[t], 0.f);
                        oq[t] = (_Float16)o;
                    }
                    *(f16x4*)(outp + (slot << 3) + (kgrp & 1) * 4) = oq;
                }
            } else {
                float part = 0.f;
                #pragma unroll
                for (int ft = 0; ft < 4; ++ft) {
                    f32x4 lgq = *(const f32x4*)&myp[64 + ft * 16 + kq];
                    f32x4 lbq = *(const f32x4*)&myp[128 + ft * 16 + kq];
                    f32x4 whq = *(const f32x4*)&pl[384 + ft * 16 + kq];
                    int slot = (ft * 2 + (kgrp >> 1)) ^ cs;
                    f16x4 rq = *(const f16x4*)(rc + (col << 6) + (slot << 3) + (kgrp & 1) * 4);
                    #pragma unroll
                    for (int t = 0; t < 4; ++t) {
                        float o = (float)rq[t]
                                + fmaxf((acc[ft][t] - mu) * rstd * lgq[t] + lbq[t], 0.f);
                        part += o * whq[t];
                    }
                }
                part += __shfl_xor(part, 16);
                part += __shfl_xor(part, 32);
                if (kgrp == 0)
                    logits[(size_t)img * NN + q * GRID_D + col] = part + bh;
            }
        }
        __syncthreads();   // lands stage (vmcnt drain) + publishes ring2 writes
    }
}

// ---------------------------------------------------------------------------
extern "C" void kernel_launch(void* const* d_in, const int* in_sizes, int n_in,
                              void* d_out, int out_size, void* d_ws, size_t ws_size,
                              hipStream_t stream) {
    const float* x      = (const float*)d_in[0];
    // d_in[1] edge_index: fixed grid 4-neighborhood -> computed as stencil, unused
    const float* w_in   = (const float*)d_in[2];
    const float* b_in   = (const float*)d_in[3];
    const float* w_self = (const float*)d_in[4];
    const float* w_neigh= (const float*)d_in[5];
    const float* conv_b = (const float*)d_in[6];
    const float* ln_g   = (const float*)d_in[7];
    const float* ln_b   = (const float*)d_in[8];
    const float* w_head = (const float*)d_in[9];
    const float* b_head = (const float*)d_in[10];
    float* out = (float*)d_out;

    char* base = (char*)d_ws;
    const size_t HBYTES = (size_t)B_SZ * NN * H * sizeof(_Float16);   // 64 MiB
    _Float16* h1  = (_Float16*)base;
    _Float16* wtb = (_Float16*)(base + HBYTES);                       // 48 KiB

    k_prep<<<96, 256, 0, stream>>>(w_self, w_neigh, wtb);
    k_inl1<<<B_SZ * GRID_D, 256, 0, stream>>>(
        x, w_in, b_in, wtb, conv_b, ln_g, ln_b, h1);
    k_fused2<<<B_SZ * 4, 512, 0, stream>>>(
        h1, out, wtb, conv_b, ln_g, ln_b, w_head, b_head);
}

// Round 14
// 143.901 us; speedup vs baseline: 1.9771x; 1.9771x over previous
//
#include <hip/hip_runtime.h>

#define GRID_D 64
#define NN (GRID_D * GRID_D)   // 4096 nodes per image
#define H 64
#define C_IN 12
#define B_SZ 128
#define LN_EPS 1e-5f

typedef _Float16 f16x8 __attribute__((ext_vector_type(8)));
typedef _Float16 f16x4 __attribute__((ext_vector_type(4)));
typedef float    f32x4 __attribute__((ext_vector_type(4)));

// dynamic LDS: ringA/ringB [4][4096] f16 (64KB) | pl[640] f32 (2.5KB)
#define SMEM_BYTES (2 * 4 * 4096 * 2 + 640 * 4)   // 68,096 B; x2 = 133KB <= 160KB

// ---------------------------------------------------------------------------
// Kernel 0: weight prep — plain-transposed f16 copies of Ws/Wn.
// wt[l][g][j][k] = W[l,g][k][j]
// ---------------------------------------------------------------------------
__global__ __launch_bounds__(256) void k_prep(
    const float* __restrict__ ws_, const float* __restrict__ wn_,
    _Float16* __restrict__ wt)
{
    int i = blockIdx.x * 256 + threadIdx.x;      // 0..24575
    if (i < 3 * 2 * 4096) {
        int l = i >> 13, g = (i >> 12) & 1, j = (i >> 6) & 63, k = i & 63;
        const float* W = (g ? wn_ : ws_) + l * 4096;
        wt[i] = (_Float16)W[k * 64 + j];
    }
}

// ---------------------------------------------------------------------------
// Kernel 1: input projection  h0[b,n,j] = sum_c x[b,c,n] * w_in[c,j] + b_in[j]
// (each h0 element computed exactly once — R13 showed per-block recompute is
// a 600-LDS-read/thread disaster)
// ---------------------------------------------------------------------------
__global__ __launch_bounds__(256) void k_inproj(
    const float* __restrict__ x, const float* __restrict__ w_in,
    const float* __restrict__ b_in, _Float16* __restrict__ h)
{
    int bid = blockIdx.x;            // b*64 + r
    int b = bid >> 6, r = bid & 63;
    __shared__ float xs[C_IN][GRID_D];
    __shared__ float ws[C_IN][H];
    int tid = threadIdx.x;
    const float* xb = x + (size_t)b * C_IN * NN + (size_t)r * GRID_D;
    for (int idx = tid; idx < C_IN * GRID_D; idx += 256) {
        int c = idx >> 6, n = idx & 63;
        xs[c][n] = xb[(size_t)c * NN + n];
        ws[c][n] = w_in[idx];
    }
    __syncthreads();
    int n = tid >> 2;                // node 0..63
    int j0 = (tid & 3) * 16;         // 16-feat group
    float acc[16];
    #pragma unroll
    for (int t = 0; t < 16; ++t) acc[t] = b_in[j0 + t];
    #pragma unroll
    for (int c = 0; c < C_IN; ++c) {
        float xv = xs[c][n];
        #pragma unroll
        for (int t = 0; t < 16; ++t) acc[t] += xv * ws[c][j0 + t];
    }
    _Float16* hp = h + (size_t)(b * NN + r * GRID_D + n) * H + j0;
    f16x8 o0, o1;
    #pragma unroll
    for (int t = 0; t < 8; ++t) { o0[t] = (_Float16)acc[t]; o1[t] = (_Float16)acc[8 + t]; }
    *(f16x8*)hp = o0;
    *(f16x8*)(hp + 8) = o1;
}

// ---------------------------------------------------------------------------
// Kernel 2: FUSED 3 layers + head, wavefront pipeline, no ring0.
// Block = 768 thr (12 waves) owns 16 output rows of one image; grid = 512
// = 2 blocks/CU IF VGPR <= 85 (launch_bounds(768,3) kept weights pinned at
// VGPR 80 in R10 — the only bound where the allocator did not demote them).
// grp0: h1 from GLOBAL h0 (rows L1/L2-hot across 3 consecutive steps)->ringA.
// grp1: h1->h2 (ringA->ringB). grp2: h2->h3+head -> logits.
// Step s (0..21): grp g computes row r0-2-2g+s; one barrier/step; mod-4 ring
// slots (writer q&3 vs reader (q-3..q-1)&3 — disjoint). Weights: 16
// f16x8/lane in VGPRs, pinned.
// ---------------------------------------------------------------------------
__global__ __launch_bounds__(768, 3) void k_fused(
    const _Float16* __restrict__ h0, float* __restrict__ logits,
    const _Float16* __restrict__ wtb,      // [3][2][64][64] transposed f16
    const float* __restrict__ cb, const float* __restrict__ lg,
    const float* __restrict__ lb,
    const float* __restrict__ w_head, const float* __restrict__ b_head)
{
    extern __shared__ _Float16 smem[];
    _Float16* ringA = smem;                     // h1 ring [4][4096]
    _Float16* ringB = smem + 16384;             // h2 ring [4][4096]
    float*    pl    = (float*)(smem + 32768);   // 640 f32

    int tid = threadIdx.x, ln = tid & 63, wv = tid >> 6;
    int bid = blockIdx.x;
    int img = bid >> 2, chunk = bid & 3;
    int r0 = chunk << 4;                   // 16 owned output rows
    const _Float16* hg = h0 + ((size_t)img << 18);

    int grp = wv >> 2;                     // 0,1,2 = layer-1,2,3
    int ct  = wv & 3;                      // col tile
    int lrow = ln & 15, kgrp = ln >> 4;
    int col = ct * 16 + lrow;
    int cs = col & 7;                      // == lrow & 7
    int kq = kgrp * 4;
    bool cl = (col > 0), cr = (col < 63);

    // ---- weights for my group's layer: 16 frags = 64 VGPR, pinned ----
    const _Float16* wg = wtb + grp * 8192;
    f16x8 wsf[2][4], wnf[2][4];
    #pragma unroll
    for (int ks = 0; ks < 2; ++ks) {
        int k0 = ks * 32 + kq * 2;         // ks*32 + kgrp*8
        #pragma unroll
        for (int ft = 0; ft < 4; ++ft) {
            int j = ft * 16 + lrow;
            wsf[ks][ft] = *(const f16x8*)(wg + (j << 6) + k0);
            wnf[ks][ft] = *(const f16x8*)(wg + ((64 + j) << 6) + k0);
        }
    }
    #pragma unroll
    for (int ks = 0; ks < 2; ++ks)
        #pragma unroll
        for (int ft = 0; ft < 4; ++ft)
            asm volatile("" : "+v"(wsf[ks][ft]), "+v"(wnf[ks][ft]));

    // ---- params to LDS ----
    if (tid < 576) {
        int l = tid / 192, r = tid % 192;
        pl[tid] = (r < 64) ? cb[l * 64 + r]
                : (r < 128) ? lg[l * 64 + r - 64] : lb[l * 64 + r - 128];
    } else if (tid < 640) {
        pl[tid] = w_head[tid - 576];
    }
    __syncthreads();

    const float* myp = pl + grp * 192;
    float bh = b_head[0];

    int qoff = -2 - 2 * grp;
    int loC, hiC;
    if (grp == 0)      { loC = (r0 - 2 < 0) ? 0 : r0 - 2; hiC = (r0 + 17 > 63) ? 63 : r0 + 17; }
    else if (grp == 1) { loC = (r0 - 1 < 0) ? 0 : r0 - 1; hiC = (r0 + 16 > 63) ? 63 : r0 + 16; }
    else               { loC = r0;                         hiC = r0 + 15; }

    const _Float16* rin = (grp == 1) ? ringA : ringB;   // grp2 reads ringB
    _Float16* rout      = (grp == 0) ? ringA : ringB;   // grp1 writes ringB

    #pragma unroll 1
    for (int s = 0; s <= 21; ++s) {
        int q = r0 + qoff + s;                 // my group's row this step
        if (q >= loC && q <= hiC) {
            _Float16 hinv = (_Float16)(1.0f / (float)((q > 0) + (q < 63) + cl + cr));
            f16x8 z = {};
            const _Float16* rp = hg + ((size_t)q << 12);    // global row (grp0)
            const _Float16* rc = rin + ((q & 3) << 12);     // ring row (grp1/2)
            const _Float16* ru = rin + (((q - 1) & 3) << 12);
            const _Float16* rd = rin + (((q + 1) & 3) << 12);

            f32x4 acc[4];
            #pragma unroll
            for (int ft = 0; ft < 4; ++ft) acc[ft] = (f32x4){0.f, 0.f, 0.f, 0.f};

            // ---- phase 1: Ws^T @ self^T ----
            #pragma unroll
            for (int ks = 0; ks < 2; ++ks) {
                f16x8 a;
                if (grp == 0) {
                    a = *(const f16x8*)(rp + (col << 6) + ks * 32 + kq * 2);
                } else {
                    int sl = ((ks * 4 + kgrp) ^ cs) << 3;
                    a = *(const f16x8*)(rc + (col << 6) + sl);
                }
                #pragma unroll
                for (int ft = 0; ft < 4; ++ft)
                    acc[ft] = __builtin_amdgcn_mfma_f32_16x16x32_f16(wsf[ks][ft], a, acc[ft], 0, 0, 0);
            }

            // ---- phase 2: Wn^T @ agg^T ----
            #pragma unroll
            for (int ks = 0; ks < 2; ++ks) {
                f16x8 u, d, l, r;
                if (grp == 0) {
                    int k0 = ks * 32 + kq * 2;
                    const _Float16* pc = rp + (col << 6) + k0;
                    u = (q > 0)  ? *(const f16x8*)(pc - 4096) : z;
                    d = (q < 63) ? *(const f16x8*)(pc + 4096) : z;
                    l = cl ? *(const f16x8*)(pc - 64) : z;
                    r = cr ? *(const f16x8*)(pc + 64) : z;
                } else {
                    int c8 = ks * 4 + kgrp;
                    int sl = (c8 ^ cs) << 3;
                    u = (q > 0)  ? *(const f16x8*)(ru + (col << 6) + sl) : z;
                    d = (q < 63) ? *(const f16x8*)(rd + (col << 6) + sl) : z;
                    int cm = col - cl;
                    l = *(const f16x8*)(rc + (cm << 6) + ((c8 ^ (cm & 7)) << 3));
                    if (!cl) l = z;
                    int cp = col + cr;
                    r = *(const f16x8*)(rc + (cp << 6) + ((c8 ^ (cp & 7)) << 3));
                    if (!cr) r = z;
                }
                f16x8 sm = (l + r) + (u + d);
                f16x8 g;
                #pragma unroll
                for (int e = 0; e < 8; ++e) g[e] = sm[e] * hinv;
                #pragma unroll
                for (int ft = 0; ft < 4; ++ft)
                    acc[ft] = __builtin_amdgcn_mfma_f32_16x16x32_f16(wnf[ks][ft], g, acc[ft], 0, 0, 0);
            }

            // ---- epilogue: +bias, LN, residual+ReLU -> ring or logits ----
            float s1 = 0.f, s2 = 0.f;
            #pragma unroll
            for (int ft = 0; ft < 4; ++ft) {
                f32x4 qv = *(const f32x4*)&myp[ft * 16 + kq];
                acc[ft] += qv;
                #pragma unroll
                for (int t = 0; t < 4; ++t) { float xv = acc[ft][t]; s1 += xv; s2 += xv * xv; }
            }
            s1 += __shfl_xor(s1, 16); s1 += __shfl_xor(s1, 32);
            s2 += __shfl_xor(s2, 16); s2 += __shfl_xor(s2, 32);
            float mu   = s1 * (1.0f / H);
            float var  = s2 * (1.0f / H) - mu * mu;
            float rstd = rsqrtf(var + LN_EPS);

            if (grp < 2) {
                _Float16* outp = rout + ((q & 3) << 12) + (col << 6);
                #pragma unroll
                for (int ft = 0; ft < 4; ++ft) {
                    f32x4 lgq = *(const f32x4*)&myp[64 + ft * 16 + kq];
                    f32x4 lbq = *(const f32x4*)&myp[128 + ft * 16 + kq];
                    int slot = (ft * 2 + (kgrp >> 1)) ^ cs;
                    f16x4 rq;
                    if (grp == 0)
                        rq = *(const f16x4*)(rp + (col << 6) + ft * 16 + kq);
                    else
                        rq = *(const f16x4*)(rc + (col << 6) + (slot << 3) + (kgrp & 1) * 4);
                    f16x4 oq;
                    #pragma unroll
                    for (int t = 0; t < 4; ++t) {
                        float o = (float)rq[t]
                                + fmaxf((acc[ft][t] - mu) * rstd * lgq[t] + lbq[t], 0.f);
                        oq[t] = (_Float16)o;
                    }
                    *(f16x4*)(outp + (slot << 3) + (kgrp & 1) * 4) = oq;
                }
            } else {
                float part = 0.f;
                #pragma unroll
                for (int ft = 0; ft < 4; ++ft) {
                    f32x4 lgq = *(const f32x4*)&myp[64 + ft * 16 + kq];
                    f32x4 lbq = *(const f32x4*)&myp[128 + ft * 16 + kq];
                    f32x4 whq = *(const f32x4*)&pl[576 + ft * 16 + kq];
                    int slot = (ft * 2 + (kgrp >> 1)) ^ cs;
                    f16x4 rq = *(const f16x4*)(rc + (col << 6) + (slot << 3) + (kgrp & 1) * 4);
                    #pragma unroll
                    for (int t = 0; t < 4; ++t) {
                        float o = (float)rq[t]
                                + fmaxf((acc[ft][t] - mu) * rstd * lgq[t] + lbq[t], 0.f);
                        part += o * whq[t];
                    }
                }
                part += __shfl_xor(part, 16);
                part += __shfl_xor(part, 32);
                if (kgrp == 0)
                    logits[(size_t)img * NN + q * GRID_D + col] = part + bh;
            }
        }
        __syncthreads();   // publishes ring writes for next step's readers
    }
}

// ---------------------------------------------------------------------------
extern "C" void kernel_launch(void* const* d_in, const int* in_sizes, int n_in,
                              void* d_out, int out_size, void* d_ws, size_t ws_size,
                              hipStream_t stream) {
    const float* x      = (const float*)d_in[0];
    // d_in[1] edge_index: fixed grid 4-neighborhood -> computed as stencil, unused
    const float* w_in   = (const float*)d_in[2];
    const float* b_in   = (const float*)d_in[3];
    const float* w_self = (const float*)d_in[4];
    const float* w_neigh= (const float*)d_in[5];
    const float* conv_b = (const float*)d_in[6];
    const float* ln_g   = (const float*)d_in[7];
    const float* ln_b   = (const float*)d_in[8];
    const float* w_head = (const float*)d_in[9];
    const float* b_head = (const float*)d_in[10];
    float* out = (float*)d_out;

    char* base = (char*)d_ws;
    const size_t HBYTES = (size_t)B_SZ * NN * H * sizeof(_Float16);   // 64 MiB
    _Float16* h_a = (_Float16*)base;
    _Float16* wtb = (_Float16*)(base + HBYTES);                       // 48 KiB

    (void)hipFuncSetAttribute(reinterpret_cast<const void*>(&k_fused),
                              hipFuncAttributeMaxDynamicSharedMemorySize, SMEM_BYTES);

    k_prep<<<96, 256, 0, stream>>>(w_self, w_neigh, wtb);
    k_inproj<<<B_SZ * GRID_D, 256, 0, stream>>>(x, w_in, b_in, h_a);
    k_fused<<<B_SZ * 4, 768, SMEM_BYTES, stream>>>(
        h_a, out, wtb, conv_b, ln_g, ln_b, w_head, b_head);
}